// Round 13
// baseline (2073.731 us; speedup 1.0000x reference)
//
#include <hip/hip_runtime.h>
#include <cstdint>
#include <cstddef>

typedef unsigned int   u32;
typedef unsigned short u16;
typedef unsigned long long u64;
typedef __attribute__((ext_vector_type(8))) short bf16x8;   // 8 bf16 = 4 VGPR
typedef __attribute__((ext_vector_type(4))) float f32x4;

#define B_  512
#define T_  168
#define H_  512

// ---------------- workspace layout (bytes) ----------------------------------
#define OFF_U1P   (0u)
#define OFF_UW2P  (2u*1024*1024)
#define OFF_FLAGS (6u*1024*1024)          // 1024 slots x 128B (per-wave flags)
#define OFF_H2R   (6u*1024*1024 + 512u*1024)  // tier-B h2 ring, 2x512KB
#define OFF_H1_R9 (8u*1024*1024)          // v9 fallback rings
#define OFF_H2_R9 (12u*1024*1024)
#define OFF_H1F   (8u*1024*1024)          // full-seq h1: 168 x 512KB (84MB)
#define SLOT_B    (524288u)
#define OFF_H2F   (OFF_H1F + 168u*SLOT_B) // full-seq h2
#define H_SLOT    262144u
#define NRING     8
#define FS        32
#define SMEM_BASE (131072 + 6144 + 3072)  // B(128K) + hlds(6K) + wlds(3K)
#define SMEM_V14  (SMEM_BASE + 16)        // + done counter
#define SMEM_V9   (SMEM_BASE)

__device__ __forceinline__ u16 f2bf(float v){
  u32 u = __float_as_uint(v);
  return (u16)((u + 0x7fffu + ((u >> 16) & 1u)) >> 16);
}
__device__ __forceinline__ float sigm_f(float x){ return __fdividef(1.f, 1.f + __expf(-x)); }
__device__ __forceinline__ float tanh_ff(float x){
  float e = __expf(-2.f*fabsf(x));
  float t = __fdividef(1.f - e, 1.f + e);
  return (x < 0.f) ? -t : t;
}
__device__ __forceinline__ void async_cp16(const void* g, void* l){
  __builtin_amdgcn_global_load_lds((const __attribute__((address_space(1))) u32*)g,
                                   (__attribute__((address_space(3))) u32*)l, 16, 0, 0);
}
__device__ __forceinline__ void drain_vm(){
  asm volatile("s_waitcnt vmcnt(0)" ::: "memory");
}

// ---------------- v17 = v16 + 8 heaters @ 768 threads (un-confounded) --------
// Trajectory: v14 (4 heaters, plain poll) 2052/2150 -> v16 (4 heaters, heated
// poll) 1963/2020. Heat-count was only tested confounded (v15: 1024-thr
// launch_bounds capped VGPR 116->64 -> compute spills). v17 single-variable:
// 8 heaters at 768 threads -- launch_bounds(768,1) = 12 waves/block = 3/SIMD
// -> ~168 VGPR cap, well above the 124 the compute path uses. Per SIMD:
// 1 compute wave (setprio 1) + 2 heaters (prio 0). If within noise of v16,
// the heat lever is fully mapped and v16/v17-best finalizes.

__device__ __forceinline__ float poll_heat(float x){       // 12-FMA filler
  #pragma unroll
  for (int i=0;i<12;i++) x = __fmaf_rn(x, 1.0001f, 1.0e-7f);
  return x;
}
__device__ __forceinline__ void wpoll(const int* p, bool act, int target, int& vlast){
  if (__all((!act) || (vlast >= target))) return;
  float hx = 1.0f; int it = 0;
  while (true){
    int v = 0x7fffffff;
    if (act) v = __hip_atomic_load(p, __ATOMIC_RELAXED, __HIP_MEMORY_SCOPE_AGENT);
    if (__all(v >= target)){ vlast = v; break; }
    hx = poll_heat(hx);                       // keep SIMD hot during the wait
    if (++it > 4) __builtin_amdgcn_s_sleep(1);
  }
  asm volatile("" :: "v"(hx));
}
template<bool PLAIN>
__device__ __forceinline__ bf16x8 ldh(const u16* p){
  if (PLAIN) return *(const bf16x8*)p;                  // cold/full-seq: always fresh
  union { u64 q[2]; bf16x8 v; } u;                      // sc1: LLC-direct
  u.q[0] = __hip_atomic_load((const u64*)p,     __ATOMIC_RELAXED, __HIP_MEMORY_SCOPE_AGENT);
  u.q[1] = __hip_atomic_load(((const u64*)p)+1, __ATOMIC_RELAXED, __HIP_MEMORY_SCOPE_AGENT);
  return u.v;
}
__device__ __forceinline__ void ring_st16(u16* p, uint4 v){   // sc1 publish (LLC)
  u64 lo = ((u64)v.y << 32) | v.x;
  u64 hi = ((u64)v.w << 32) | v.z;
  __hip_atomic_store((u64*)p,     lo, __ATOMIC_RELAXED, __HIP_MEMORY_SCOPE_AGENT);
  __hip_atomic_store(((u64*)p)+1, hi, __ATOMIC_RELAXED, __HIP_MEMORY_SCOPE_AGENT);
}

// ---------------- weight packing ---------------------------------------------
__global__ void pack_w_kernel(const float* __restrict__ U1, const float* __restrict__ W2,
                              const float* __restrict__ U2, u16* __restrict__ U1p,
                              u16* __restrict__ UW2p)
{
  int idx = blockIdx.x*256 + threadIdx.x;
  int ln = idx & 63;
  int q8 = ((ln >> 4) << 3);
  int cl = ln & 15;
  if (idx < 16*128*64) {
    int kc = idx >> 13, ng = (idx >> 6) & 127;
    int row0 = kc*32 + q8, col = ng*16 + cl;
    u16* d = U1p + (size_t)idx*8;
    #pragma unroll
    for (int j=0;j<8;j++) d[j] = f2bf(U1[(size_t)(row0+j)*2048 + col]);
  } else {
    int i2 = idx - 16*128*64;
    if (i2 >= 32*128*64) return;
    int kc = i2 >> 13, ng = (i2 >> 6) & 127;
    int row0 = kc*32 + q8, col = ng*16 + cl;
    u16* d = UW2p + (size_t)i2*8;
    #pragma unroll
    for (int j=0;j<8;j++){
      int r = row0 + j;
      float v = (r < 512) ? W2[(size_t)r*2048 + col] : U2[(size_t)(r-512)*2048 + col];
      d[j] = f2bf(v);
    }
  }
}

__global__ void init_kernel(float* __restrict__ out, const float* __restrict__ fcb,
                            int* __restrict__ flags)
{
  int i = blockIdx.x*256 + threadIdx.x;
  if (i < 1024*FS) flags[i] = 0;
  if (i < B_*T_) out[i] = fcb[0];
}

// ============================ layer 1 (v10 structure) ========================
__device__ void run_l1_fs(char* smem, int blk, const float* __restrict__ inp,
                          const float* __restrict__ W1, const float* __restrict__ V,
                          const float* __restrict__ bias, char* __restrict__ ws)
{
  u16*  Bl   = (u16*)smem;                        // [16kc][8ngl][512]
  u16*  hlds = (u16*)(smem + 131072);             // 64 x 40
  float* wlds = (float*)(smem + 131072 + 6144);   // 4*32*6
  constexpr int RS = 40;
  const int tid = threadIdx.x, w = tid>>6, ln = tid&63, col = ln&15, quad = ln>>4;
  const int bi = blk & 7, hj = blk >> 3, h0 = hj*32, bg = bi*4 + w;

  const u16* Upak = (const u16*)(ws + OFF_U1P);
  const u16* H1f  = (const u16*)(ws + OFF_H1F);
  u16* Hw = (u16*)(ws + OFF_H1F);
  int* flag1 = (int*)(ws + OFF_FLAGS);
  const int* f1p = flag1 + (size_t)((bi*16 + (ln&15))*4 + w)*FS;  // producers, wave w
  int* myf = flag1 + (size_t)((bi*16 + hj)*4 + w)*FS;
  const bool a16 = ln < 16;
  int vl1 = 0;

  #pragma unroll
  for (int p=0;p<32;p++){
    int pid = w*32 + p, kc = pid>>3, ngl = pid&7;
    int ng = (ngl>>1)*32 + hj*2 + (ngl&1);
    async_cp16(Upak + ((size_t)(kc*128+ng)*64 + ln)*8, Bl + (size_t)pid*512);
  }
  for (int idx=tid; idx<4*32*6; idx+=256){
    int gate = idx/192, rem = idx%192, hcol = rem/6, k = rem%6;
    int gcol = gate*512 + h0 + hcol;
    wlds[idx] = (k==0)? bias[gcol] : (k<=4 ? V[(size_t)(k-1)*2048 + gcol] : W1[gcol]);
  }
  if (tid == 0) *(int*)(smem + SMEM_BASE) = 0;    // done counter

  float c[8];
  #pragma unroll
  for (int i=0;i<8;i++) c[i] = 0.f;
  const f32x4 vzero = {0.f,0.f,0.f,0.f};

  __syncthreads();   // one-time (heater waves join this barrier)
  __builtin_amdgcn_s_setprio(1);                  // compute waves: high prio

  for (int t=0; t<T_; t++){
    f32x4 acc[8];
    #pragma unroll
    for (int i=0;i<8;i++) acc[i] = vzero;

    if (t > 0){
      wpoll(f1p, a16, t, vl1);                              // per-wave, no barrier
      __builtin_amdgcn_fence(__ATOMIC_ACQUIRE, "workgroup");
      const u16* ab = H1f + (size_t)(t-1)*H_SLOT + (size_t)bg*16*512 + (size_t)ln*8;
      bf16x8 aw[8];
      #pragma unroll
      for (int i=0;i<8;i++) aw[i] = ldh<true>(ab + (size_t)i*512);
      #pragma unroll
      for (int kc=0; kc<16; kc++){
        bf16x8 av = aw[kc&7];
        if (kc < 8) aw[kc&7] = ldh<true>(ab + (size_t)(kc+8)*512);
        const u16* bb = Bl + (size_t)kc*8*512 + (size_t)ln*8;
        #pragma unroll
        for (int ngl=0; ngl<8; ngl++)
          acc[ngl] = __builtin_amdgcn_mfma_f32_16x16x32_bf16(
              av, *(const bf16x8*)(bb + (size_t)ngl*512), acc[ngl], 0,0,0);
      }
    }

    float iv[4][5];
    #pragma unroll
    for (int r=0;r<4;r++){
      const float* ip = inp + ((size_t)(bi*64 + w*16 + quad*4 + r)*T_ + t)*5;
      #pragma unroll
      for (int k=0;k<5;k++) iv[r][k] = ip[k];
    }
    #pragma unroll
    for (int hg=0; hg<2; hg++){
      float wv[4][6];
      #pragma unroll
      for (int gate=0; gate<4; gate++){
        const float* wp = wlds + (size_t)(gate*32 + hg*16 + col)*6;
        #pragma unroll
        for (int k=0;k<6;k++) wv[gate][k] = wp[k];
      }
      #pragma unroll
      for (int r=0;r<4;r++){
        float gv[4];
        #pragma unroll
        for (int gate=0; gate<4; gate++){
          gv[gate] = acc[gate*2+hg][r] + wv[gate][0]
                   + iv[r][0]*wv[gate][1] + iv[r][1]*wv[gate][2]
                   + iv[r][2]*wv[gate][3] + iv[r][3]*wv[gate][4]
                   + iv[r][4]*wv[gate][5];
        }
        float ig=sigm_f(gv[0]), fg=sigm_f(gv[1]), gg=tanh_ff(gv[2]), og=sigm_f(gv[3]);
        float cn = fg*c[hg*4+r] + ig*gg;
        c[hg*4+r] = cn;
        hlds[(size_t)(w*16 + quad*4 + r)*RS + hg*16 + col] = f2bf(og*tanh_ff(cn));
      }
    }
    // pack: same-wave transpose (wave-local rows, no barrier)
    {
      uint4 v = *(const uint4*)&hlds[(size_t)(w*16 + (ln&15))*RS + (ln>>4)*8];
      ring_st16(Hw + (size_t)t*H_SLOT + ((size_t)(bg*16 + hj)*64 + ln)*8, v);
    }
    drain_vm();
    if (ln == 0)
      __hip_atomic_store(myf, t+1, __ATOMIC_RELAXED, __HIP_MEMORY_SCOPE_AGENT);
  }
  if (ln == 0) atomicAdd((int*)(smem + SMEM_BASE), 1);   // signal heaters
}

// ============================ layer 2 (v10 structure) ========================
template<bool PLAIN>
__device__ __forceinline__ void l2_half(f32x4* accA, f32x4* accB, const u16* Bh,
                                        const u16* A, int bgA, int bgB, int ln)
{
  const u16* pA = A + (size_t)bgA*16*512 + (size_t)ln*8;
  const u16* pB = A + (size_t)bgB*16*512 + (size_t)ln*8;
  bf16x8 awA[8], awB[8];
  #pragma unroll
  for (int i=0;i<8;i++){
    awA[i] = ldh<PLAIN>(pA + (size_t)i*512);
    awB[i] = ldh<PLAIN>(pB + (size_t)i*512);
  }
  #pragma unroll
  for (int kc=0; kc<16; kc++){
    bf16x8 avA = awA[kc&7], avB = awB[kc&7];
    if (kc < 8){
      awA[kc&7] = ldh<PLAIN>(pA + (size_t)(kc+8)*512);
      awB[kc&7] = ldh<PLAIN>(pB + (size_t)(kc+8)*512);
    }
    const u16* bb = Bh + (size_t)kc*4*512 + (size_t)ln*8;
    #pragma unroll
    for (int ngl=0; ngl<4; ngl++){
      bf16x8 bf = *(const bf16x8*)(bb + (size_t)ngl*512);
      accA[ngl] = __builtin_amdgcn_mfma_f32_16x16x32_bf16(avA, bf, accA[ngl], 0,0,0);
      accB[ngl] = __builtin_amdgcn_mfma_f32_16x16x32_bf16(avB, bf, accB[ngl], 0,0,0);
    }
  }
}

template<bool H2F>
__device__ void run_l2_fs(char* smem, int blk2, const float* __restrict__ inp,
                          const float* __restrict__ V, const float* __restrict__ bias,
                          const float* __restrict__ fcw, char* __restrict__ ws,
                          float* __restrict__ out)
{
  u16*  Bl   = (u16*)smem;                        // [32kc][4ngl][512]
  u16*  hlds = (u16*)(smem + 131072);             // 128 x 24
  float* wlds = (float*)(smem + 131072 + 6144);   // 4*16*6
  constexpr int RS = 24;
  const int tid = threadIdx.x, w = tid>>6, ln = tid&63, col = ln&15, quad = ln>>4;
  const int bi2 = blk2 & 3, hj = blk2 >> 2, h0 = hj*16;
  const int bgA = bi2*8 + w, bgB = bgA + 4;

  const u16* Upak = (const u16*)(ws + OFF_UW2P);
  const u16* H1f  = (const u16*)(ws + OFF_H1F);
  const u16* H2b  = (const u16*)(ws + (H2F ? OFF_H2F : OFF_H2R));
  u16* Hw = (u16*)(ws + (H2F ? OFF_H2F : OFF_H2R));
  int* flag1 = (int*)(ws + OFF_FLAGS);
  int* flag2 = flag1 + 512*FS;
  const int* h1f = flag1 + (size_t)((bi2*32 + (ln&31))*4 + w)*FS;
  const int* h2f = flag2 + (size_t)((bi2*32 + (ln&31))*4 + w)*FS;
  int* myf = flag2 + (size_t)((bi2*32 + hj)*4 + w)*FS;
  const bool a32 = ln < 32;
  int vlh1 = 0, vlh2 = 0;

  #pragma unroll
  for (int p=0;p<32;p++){
    int pid = w*32 + p, kc = pid>>2, ngl = pid&3;
    int ng = ngl*32 + hj;
    async_cp16(Upak + ((size_t)(kc*128+ng)*64 + ln)*8, Bl + (size_t)pid*512);
  }
  for (int idx=tid; idx<4*16*6; idx+=256){
    int gate = idx/96, rem = idx%96, hcol = rem/6, k = rem%6;
    int gcol = gate*512 + h0 + hcol;
    wlds[idx] = (k==0)? bias[gcol] : (k<=4 ? V[(size_t)(k-1)*2048 + gcol] : 0.f);
  }
  const float fcwr = fcw[h0 + col];
  if (tid == 0) *(int*)(smem + SMEM_BASE) = 0;

  float c[8];
  #pragma unroll
  for (int i=0;i<8;i++) c[i] = 0.f;
  const f32x4 vzero = {0.f,0.f,0.f,0.f};

  __syncthreads();   // heater waves join
  __builtin_amdgcn_s_setprio(1);

  for (int t=0; t<T_; t++){
    f32x4 accA[4], accB[4];
    #pragma unroll
    for (int i=0;i<4;i++){ accA[i] = vzero; accB[i] = vzero; }

    wpoll(h1f, a32, t+1, vlh1);
    __builtin_amdgcn_fence(__ATOMIC_ACQUIRE, "workgroup");
    const u16* A1 = H1f + (size_t)t*H_SLOT;
    l2_half<true>(accA, accB, Bl, A1, bgA, bgB, ln);

    if (t > 0){
      wpoll(h2f, a32, t, vlh2);
      __builtin_amdgcn_fence(__ATOMIC_ACQUIRE, "workgroup");
      const u16* A2 = H2b + (H2F ? (size_t)(t-1)*H_SLOT : (size_t)((t-1)&1)*H_SLOT);
      l2_half<H2F>(accA, accB, Bl + (size_t)16*4*512, A2, bgA, bgB, ln);
    }

    float wv[4][5];
    #pragma unroll
    for (int gate=0; gate<4; gate++){
      const float* wp = wlds + (size_t)(gate*16 + col)*6;
      #pragma unroll
      for (int k=0;k<5;k++) wv[gate][k] = wp[k];
    }
    float fcp[2][4];
    #pragma unroll
    for (int sel=0; sel<2; sel++){
      const f32x4* ac = sel ? accB : accA;
      #pragma unroll
      for (int r=0;r<4;r++){
        const float* ip = inp + ((size_t)(bi2*128 + sel*64 + w*16 + quad*4 + r)*T_ + t)*5;
        float i0=ip[0], i1=ip[1], i2=ip[2], i3=ip[3];
        float gv[4];
        #pragma unroll
        for (int gate=0; gate<4; gate++){
          gv[gate] = ac[gate][r] + wv[gate][0]
                   + i0*wv[gate][1] + i1*wv[gate][2] + i2*wv[gate][3] + i3*wv[gate][4];
        }
        float ig=sigm_f(gv[0]), fg=sigm_f(gv[1]), gg=tanh_ff(gv[2]), og=sigm_f(gv[3]);
        float cn = fg*c[sel*4+r] + ig*gg;
        c[sel*4+r] = cn;
        float h = og*tanh_ff(cn);
        fcp[sel][r] = h*fcwr;
        hlds[(size_t)(sel*64 + w*16 + quad*4 + r)*RS + col] = f2bf(h);
      }
    }
    // publish h2[t] (same-wave transpose)
    {
      int sel = ln>>5, ch = (ln>>4)&1, m = ln&15;
      uint4 v = *(const uint4*)&hlds[(size_t)(sel*64 + w*16 + m)*RS + ch*8];
      int lp = ((hj&1)*2 + ch)*16 + m;
      int bgx = bi2*8 + sel*4 + w;
      u16* dst = Hw + (H2F ? (size_t)t*H_SLOT : (size_t)(t&1)*H_SLOT)
               + ((size_t)(bgx*16 + (hj>>1))*64 + lp)*8;
      ring_st16(dst, v);
    }
    drain_vm();
    if (ln == 0)
      __hip_atomic_store(myf, t+1, __ATOMIC_RELAXED, __HIP_MEMORY_SCOPE_AGENT);

    #pragma unroll
    for (int sel=0; sel<2; sel++){
      #pragma unroll
      for (int r=0;r<4;r++){
        float v = fcp[sel][r];
        #pragma unroll
        for (int m=1;m<16;m<<=1) v += __shfl_xor(v, m, 16);
        if (col == 0)
          atomicAdd(&out[(size_t)(bi2*128 + sel*64 + w*16 + quad*4 + r)*T_ + t], v);
      }
    }
  }
  if (ln == 0) atomicAdd((int*)(smem + SMEM_BASE), 1);
}

// ============================ heater waves ===================================
__device__ void heater(char* smem)
{
  volatile int* done = (int*)(smem + SMEM_BASE);
  __syncthreads();                          // join the one-time barrier
  float a = 1.0001f, b = 0.9999f, c0 = 1.0002f, d = 1.0003f, e = 0.9997f;
  while (*done < 4){
    #pragma unroll
    for (int i=0;i<64;i++){
      a  = __fmaf_rn(a,  b, 1.0e-7f);
      c0 = __fmaf_rn(c0, d, 1.0e-7f);
      e  = __fmaf_rn(e,  b, 1.0e-7f);
    }
    asm volatile("" :: "v"(a), "v"(c0), "v"(e));
  }
}

template<bool H2F>
__global__ void __launch_bounds__(768, 1)
lstm_main_v17(const float* __restrict__ inp, const float* __restrict__ W1,
              const float* __restrict__ V1, const float* __restrict__ b1,
              const float* __restrict__ V2, const float* __restrict__ b2,
              const float* __restrict__ fcw, char* __restrict__ ws, float* __restrict__ out)
{
  extern __shared__ char smem[];
  int blk = blockIdx.x;
  if (threadIdx.x >= 256){ heater(smem); return; }
  if (blk < 128) run_l1_fs(smem, blk, inp, W1, V1, b1, ws);
  else           run_l2_fs<H2F>(smem, blk-128, inp, V2, b2, fcw, ws, out);
}

// =========================== v9 fallback (proven 2221us, 256 thr) ============
__device__ void run_l1_r9(char* smem, int blk, const float* __restrict__ inp,
                          const float* __restrict__ W1, const float* __restrict__ V,
                          const float* __restrict__ bias, char* __restrict__ ws)
{
  u16*  Bl   = (u16*)smem;
  u16*  hlds = (u16*)(smem + 131072);
  float* wlds = (float*)(smem + 131072 + 6144);
  constexpr int RS = 40;
  const int tid = threadIdx.x, w = tid>>6, ln = tid&63, col = ln&15, quad = ln>>4;
  const int bi = blk & 7, hj = blk >> 3, h0 = hj*32, bg = bi*4 + w;

  const u16* Upak = (const u16*)(ws + OFF_U1P);
  const u16* H1r  = (const u16*)(ws + OFF_H1_R9);
  u16* Hw = (u16*)(ws + OFF_H1_R9);
  int* flag1 = (int*)(ws + OFF_FLAGS);
  int* flag2 = flag1 + 128*FS;
  const int* f1p = flag1 + (size_t)(bi*16 + (ln&15))*FS;
  const int* f2p = flag2 + (size_t)((bi>>1)*32 + (ln&31))*FS;
  int* myf = flag1 + (size_t)(bi*16 + hj)*FS;
  const bool a16 = ln < 16, a32 = ln < 32;
  int vl1 = 0, vlbp = 0;

  #pragma unroll
  for (int p=0;p<32;p++){
    int pid = w*32 + p, kc = pid>>3, ngl = pid&7;
    int ng = (ngl>>1)*32 + hj*2 + (ngl&1);
    async_cp16(Upak + ((size_t)(kc*128+ng)*64 + ln)*8, Bl + (size_t)pid*512);
  }
  for (int idx=tid; idx<4*32*6; idx+=256){
    int gate = idx/192, rem = idx%192, hcol = rem/6, k = rem%6;
    int gcol = gate*512 + h0 + hcol;
    wlds[idx] = (k==0)? bias[gcol] : (k<=4 ? V[(size_t)(k-1)*2048 + gcol] : W1[gcol]);
  }

  float c[8];
  #pragma unroll
  for (int i=0;i<8;i++) c[i] = 0.f;
  const f32x4 vzero = {0.f,0.f,0.f,0.f};

  for (int t=0; t<T_; t++){
    if (w == 0){
      if (t > 0)      wpoll(f1p, a16, t, vl1);
      if (t >= NRING) wpoll(f2p, a32, t-NRING+1, vlbp);
      __builtin_amdgcn_fence(__ATOMIC_ACQUIRE, "agent");
    }
    __syncthreads();

    f32x4 acc[8];
    #pragma unroll
    for (int i=0;i<8;i++) acc[i] = vzero;

    if (t > 0){
      const u16* ab = H1r + (size_t)((t-1)&7)*H_SLOT + (size_t)bg*16*512 + (size_t)ln*8;
      bf16x8 aw[8];
      #pragma unroll
      for (int i=0;i<8;i++) aw[i] = ldh<true>(ab + (size_t)i*512);
      #pragma unroll
      for (int kc=0; kc<16; kc++){
        bf16x8 av = aw[kc&7];
        if (kc < 8) aw[kc&7] = ldh<true>(ab + (size_t)(kc+8)*512);
        const u16* bb = Bl + (size_t)kc*8*512 + (size_t)ln*8;
        #pragma unroll
        for (int ngl=0; ngl<8; ngl++)
          acc[ngl] = __builtin_amdgcn_mfma_f32_16x16x32_bf16(
              av, *(const bf16x8*)(bb + (size_t)ngl*512), acc[ngl], 0,0,0);
      }
    }

    float iv[4][5];
    #pragma unroll
    for (int r=0;r<4;r++){
      const float* ip = inp + ((size_t)(bi*64 + w*16 + quad*4 + r)*T_ + t)*5;
      #pragma unroll
      for (int k=0;k<5;k++) iv[r][k] = ip[k];
    }
    #pragma unroll
    for (int hg=0; hg<2; hg++){
      float wv[4][6];
      #pragma unroll
      for (int gate=0; gate<4; gate++){
        const float* wp = wlds + (size_t)(gate*32 + hg*16 + col)*6;
        #pragma unroll
        for (int k=0;k<6;k++) wv[gate][k] = wp[k];
      }
      #pragma unroll
      for (int r=0;r<4;r++){
        float gv[4];
        #pragma unroll
        for (int gate=0; gate<4; gate++){
          gv[gate] = acc[gate*2+hg][r] + wv[gate][0]
                   + iv[r][0]*wv[gate][1] + iv[r][1]*wv[gate][2]
                   + iv[r][2]*wv[gate][3] + iv[r][3]*wv[gate][4]
                   + iv[r][4]*wv[gate][5];
        }
        float ig=sigm_f(gv[0]), fg=sigm_f(gv[1]), gg=tanh_ff(gv[2]), og=sigm_f(gv[3]);
        float cn = fg*c[hg*4+r] + ig*gg;
        c[hg*4+r] = cn;
        hlds[(size_t)(w*16 + quad*4 + r)*RS + hg*16 + col] = f2bf(og*tanh_ff(cn));
      }
    }
    {
      uint4 v = *(const uint4*)&hlds[(size_t)(w*16 + (ln&15))*RS + (ln>>4)*8];
      ring_st16(Hw + (size_t)(t&7)*H_SLOT + ((size_t)(bg*16 + hj)*64 + ln)*8, v);
    }
    __syncthreads();
    if (tid==0){
      __builtin_amdgcn_fence(__ATOMIC_RELEASE, "workgroup");
      __hip_atomic_store(myf, t+1, __ATOMIC_RELAXED, __HIP_MEMORY_SCOPE_AGENT);
    }
  }
}

__device__ void run_l2_r9(char* smem, int blk2, const float* __restrict__ inp,
                          const float* __restrict__ V, const float* __restrict__ bias,
                          const float* __restrict__ fcw, char* __restrict__ ws,
                          float* __restrict__ out)
{
  u16*  Bl   = (u16*)smem;
  u16*  hlds = (u16*)(smem + 131072);
  float* wlds = (float*)(smem + 131072 + 6144);
  constexpr int RS = 24;
  const int tid = threadIdx.x, w = tid>>6, ln = tid&63, col = ln&15, quad = ln>>4;
  const int bi2 = blk2 & 3, hj = blk2 >> 2, h0 = hj*16;
  const int bgA = bi2*8 + w, bgB = bgA + 4;

  const u16* Upak = (const u16*)(ws + OFF_UW2P);
  const u16* H1r  = (const u16*)(ws + OFF_H1_R9);
  const u16* H2r  = (const u16*)(ws + OFF_H2_R9);
  u16* Hw = (u16*)(ws + OFF_H2_R9);
  int* flag1 = (int*)(ws + OFF_FLAGS);
  int* flag2 = flag1 + 128*FS;
  const int* h1f = flag1 + (size_t)(bi2*32 + (ln&31))*FS;
  const int* h2f = flag2 + (size_t)(bi2*32 + (ln&31))*FS;
  int* myf = flag2 + (size_t)(bi2*32 + hj)*FS;
  const bool a32 = ln < 32;
  int vlh1 = 0, vlh2 = 0;

  #pragma unroll
  for (int p=0;p<32;p++){
    int pid = w*32 + p, kc = pid>>2, ngl = pid&3;
    int ng = ngl*32 + hj;
    async_cp16(Upak + ((size_t)(kc*128+ng)*64 + ln)*8, Bl + (size_t)pid*512);
  }
  for (int idx=tid; idx<4*16*6; idx+=256){
    int gate = idx/96, rem = idx%96, hcol = rem/6, k = rem%6;
    int gcol = gate*512 + h0 + hcol;
    wlds[idx] = (k==0)? bias[gcol] : (k<=4 ? V[(size_t)(k-1)*2048 + gcol] : 0.f);
  }
  const float fcwr = fcw[h0 + col];

  float c[8];
  #pragma unroll
  for (int i=0;i<8;i++) c[i] = 0.f;
  const f32x4 vzero = {0.f,0.f,0.f,0.f};

  for (int t=0; t<T_; t++){
    if (w == 0){
      wpoll(h1f, a32, t+1, vlh1);
      __builtin_amdgcn_fence(__ATOMIC_ACQUIRE, "agent");
    }
    __syncthreads();

    f32x4 accA[4], accB[4];
    #pragma unroll
    for (int i=0;i<4;i++){ accA[i] = vzero; accB[i] = vzero; }

    const u16* A1 = H1r + (size_t)(t&7)*H_SLOT;
    l2_half<true>(accA, accB, Bl, A1, bgA, bgB, ln);

    if (t > 0){
      wpoll(h2f, a32, t, vlh2);
      __builtin_amdgcn_fence(__ATOMIC_ACQUIRE, "workgroup");
      const u16* A2 = H2r + (size_t)((t-1)&1)*H_SLOT;
      l2_half<false>(accA, accB, Bl + (size_t)16*4*512, A2, bgA, bgB, ln);
    }

    float wv[4][5];
    #pragma unroll
    for (int gate=0; gate<4; gate++){
      const float* wp = wlds + (size_t)(gate*16 + col)*6;
      #pragma unroll
      for (int k=0;k<5;k++) wv[gate][k] = wp[k];
    }
    float fcp[2][4];
    #pragma unroll
    for (int sel=0; sel<2; sel++){
      const f32x4* ac = sel ? accB : accA;
      #pragma unroll
      for (int r=0;r<4;r++){
        const float* ip = inp + ((size_t)(bi2*128 + sel*64 + w*16 + quad*4 + r)*T_ + t)*5;
        float i0=ip[0], i1=ip[1], i2=ip[2], i3=ip[3];
        float gv[4];
        #pragma unroll
        for (int gate=0; gate<4; gate++){
          gv[gate] = ac[gate][r] + wv[gate][0]
                   + i0*wv[gate][1] + i1*wv[gate][2] + i2*wv[gate][3] + i3*wv[gate][4];
        }
        float ig=sigm_f(gv[0]), fg=sigm_f(gv[1]), gg=tanh_ff(gv[2]), og=sigm_f(gv[3]);
        float cn = fg*c[sel*4+r] + ig*gg;
        c[sel*4+r] = cn;
        float h = og*tanh_ff(cn);
        fcp[sel][r] = h*fcwr;
        hlds[(size_t)(sel*64 + w*16 + quad*4 + r)*RS + col] = f2bf(h);
      }
    }
    {
      int sel = ln>>5, ch = (ln>>4)&1, m = ln&15;
      uint4 v = *(const uint4*)&hlds[(size_t)(sel*64 + w*16 + m)*RS + ch*8];
      int lp = ((hj&1)*2 + ch)*16 + m;
      int bgx = bi2*8 + sel*4 + w;
      ring_st16(Hw + (size_t)(t&1)*H_SLOT + ((size_t)(bgx*16 + (hj>>1))*64 + lp)*8, v);
    }
    __syncthreads();
    if (tid==0){
      __builtin_amdgcn_fence(__ATOMIC_RELEASE, "workgroup");
      __hip_atomic_store(myf, t+1, __ATOMIC_RELAXED, __HIP_MEMORY_SCOPE_AGENT);
    }

    #pragma unroll
    for (int sel=0; sel<2; sel++){
      #pragma unroll
      for (int r=0;r<4;r++){
        float v = fcp[sel][r];
        #pragma unroll
        for (int m=1;m<16;m<<=1) v += __shfl_xor(v, m, 16);
        if (col == 0)
          atomicAdd(&out[(size_t)(bi2*128 + sel*64 + w*16 + quad*4 + r)*T_ + t], v);
      }
    }
  }
}

__global__ void __launch_bounds__(256, 1)
lstm_main_v9fb(const float* __restrict__ inp, const float* __restrict__ W1,
               const float* __restrict__ V1, const float* __restrict__ b1,
               const float* __restrict__ V2, const float* __restrict__ b2,
               const float* __restrict__ fcw, char* __restrict__ ws, float* __restrict__ out)
{
  extern __shared__ char smem[];
  int blk = blockIdx.x;
  if (blk < 128) run_l1_r9(smem, blk, inp, W1, V1, b1, ws);
  else           run_l2_r9(smem, blk-128, inp, V2, b2, fcw, ws, out);
}

extern "C" void kernel_launch(void* const* d_in, const int* in_sizes, int n_in,
                              void* d_out, int out_size, void* d_ws, size_t ws_size,
                              hipStream_t stream) {
  (void)in_sizes; (void)n_in; (void)out_size;
  const float* inp = (const float*)d_in[0];
  const float* W1  = (const float*)d_in[1];
  const float* U1  = (const float*)d_in[2];
  const float* V1  = (const float*)d_in[3];
  const float* b1  = (const float*)d_in[4];
  const float* W2  = (const float*)d_in[5];
  const float* U2  = (const float*)d_in[6];
  const float* V2  = (const float*)d_in[7];
  const float* b2  = (const float*)d_in[8];
  const float* fcw = (const float*)d_in[9];
  const float* fcb = (const float*)d_in[10];
  char* ws = (char*)d_ws;
  float* out = (float*)d_out;

  pack_w_kernel<<<1536, 256, 0, stream>>>(U1, W2, U2,
      (u16*)(ws + OFF_U1P), (u16*)(ws + OFF_UW2P));
  init_kernel<<<(B_*T_ + 255)/256, 256, 0, stream>>>(out, fcb, (int*)(ws + OFF_FLAGS));

  const size_t need_h1f  = (size_t)OFF_H1F + (size_t)T_*SLOT_B;   // ~92 MB
  const size_t need_both = (size_t)OFF_H2F + (size_t)T_*SLOT_B;   // ~176 MB

  if (ws_size >= need_both) {
    (void)hipFuncSetAttribute((const void*)lstm_main_v17<true>,
                              hipFuncAttributeMaxDynamicSharedMemorySize, SMEM_V14);
    lstm_main_v17<true><<<256, 768, SMEM_V14, stream>>>(inp, W1, V1, b1, V2, b2, fcw, ws, out);
  } else if (ws_size >= need_h1f) {
    (void)hipFuncSetAttribute((const void*)lstm_main_v17<false>,
                              hipFuncAttributeMaxDynamicSharedMemorySize, SMEM_V14);
    lstm_main_v17<false><<<256, 768, SMEM_V14, stream>>>(inp, W1, V1, b1, V2, b2, fcw, ws, out);
  } else {
    (void)hipFuncSetAttribute((const void*)lstm_main_v9fb,
                              hipFuncAttributeMaxDynamicSharedMemorySize, SMEM_V9);
    lstm_main_v9fb<<<256, 256, SMEM_V9, stream>>>(inp, W1, V1, b1, V2, b2, fcw, ws, out);
  }
}

// Round 14
// 1959.170 us; speedup vs baseline: 1.0585x; 1.0585x over previous
//
#include <hip/hip_runtime.h>
#include <cstdint>
#include <cstddef>

typedef unsigned int   u32;
typedef unsigned short u16;
typedef unsigned long long u64;
typedef __attribute__((ext_vector_type(8))) short bf16x8;   // 8 bf16 = 4 VGPR
typedef __attribute__((ext_vector_type(4))) float f32x4;

#define B_  512
#define T_  168
#define H_  512

// ---------------- workspace layout (bytes) ----------------------------------
#define OFF_U1P   (0u)
#define OFF_UW2P  (2u*1024*1024)
#define OFF_FLAGS (6u*1024*1024)          // 1024 slots x 128B (per-wave flags)
#define OFF_H2R   (6u*1024*1024 + 512u*1024)  // tier-B h2 ring, 2x512KB
#define OFF_H1_R9 (8u*1024*1024)          // v9 fallback rings
#define OFF_H2_R9 (12u*1024*1024)
#define OFF_H1F   (8u*1024*1024)          // full-seq h1: 168 x 512KB (84MB)
#define SLOT_B    (524288u)
#define OFF_H2F   (OFF_H1F + 168u*SLOT_B) // full-seq h2
#define H_SLOT    262144u
#define NRING     8
#define FS        32
#define SMEM_BASE (131072 + 6144 + 3072)  // B(128K) + hlds(6K) + wlds(3K)
#define SMEM_V14  (SMEM_BASE + 16)        // + done counter
#define SMEM_V9   (SMEM_BASE)

__device__ __forceinline__ u16 f2bf(float v){
  u32 u = __float_as_uint(v);
  return (u16)((u + 0x7fffu + ((u >> 16) & 1u)) >> 16);
}
__device__ __forceinline__ float sigm_f(float x){ return __fdividef(1.f, 1.f + __expf(-x)); }
__device__ __forceinline__ float tanh_ff(float x){
  float e = __expf(-2.f*fabsf(x));
  float t = __fdividef(1.f - e, 1.f + e);
  return (x < 0.f) ? -t : t;
}
__device__ __forceinline__ void async_cp16(const void* g, void* l){
  __builtin_amdgcn_global_load_lds((const __attribute__((address_space(1))) u32*)g,
                                   (__attribute__((address_space(3))) u32*)l, 16, 0, 0);
}
__device__ __forceinline__ void drain_vm(){
  asm volatile("s_waitcnt vmcnt(0)" ::: "memory");
}

// ---------------- v16-FINAL (session result) ---------------------------------
// Session map: eight structural sync/memory-model variants (RMW/store flags,
// barriers/none, inv/wbl2/none, ring/full-seq cold addresses, sc1/plain,
// bulk/per-chunk dataflow gating) were all null at 13-15us/step -- the
// recurrence handoff is a latency floor under platform clock behavior, not a
// memory-model or dataflow property (MfmaUtil 11%, HBM 4%: no classical
// roofline). The real levers, both clock/activity-side:
//   - 4 heater waves/block (v14): 2388 -> 2150 steady
//   - heated hybrid-backoff polls (v16): -> 2012-2053 steady, 1963 headline
// More heat regressed twice (v15: VGPR 116->64; v17: VGPR 124->84 -- both
// launch_bounds-induced compute spills; and v15 showed heat saturates ~55%
// VALUBusy even when running). This file is v16 verbatim: 512-thr blocks,
// 4 heaters, heated polls, VGPR 124, v10 full-seq skeleton, v9 fallback.

__device__ __forceinline__ float poll_heat(float x){       // 12-FMA filler
  #pragma unroll
  for (int i=0;i<12;i++) x = __fmaf_rn(x, 1.0001f, 1.0e-7f);
  return x;
}
__device__ __forceinline__ void wpoll(const int* p, bool act, int target, int& vlast){
  if (__all((!act) || (vlast >= target))) return;
  float hx = 1.0f; int it = 0;
  while (true){
    int v = 0x7fffffff;
    if (act) v = __hip_atomic_load(p, __ATOMIC_RELAXED, __HIP_MEMORY_SCOPE_AGENT);
    if (__all(v >= target)){ vlast = v; break; }
    hx = poll_heat(hx);                       // keep SIMD hot during the wait
    if (++it > 4) __builtin_amdgcn_s_sleep(1);
  }
  asm volatile("" :: "v"(hx));
}
template<bool PLAIN>
__device__ __forceinline__ bf16x8 ldh(const u16* p){
  if (PLAIN) return *(const bf16x8*)p;                  // cold/full-seq: always fresh
  union { u64 q[2]; bf16x8 v; } u;                      // sc1: LLC-direct
  u.q[0] = __hip_atomic_load((const u64*)p,     __ATOMIC_RELAXED, __HIP_MEMORY_SCOPE_AGENT);
  u.q[1] = __hip_atomic_load(((const u64*)p)+1, __ATOMIC_RELAXED, __HIP_MEMORY_SCOPE_AGENT);
  return u.v;
}
__device__ __forceinline__ void ring_st16(u16* p, uint4 v){   // sc1 publish (LLC)
  u64 lo = ((u64)v.y << 32) | v.x;
  u64 hi = ((u64)v.w << 32) | v.z;
  __hip_atomic_store((u64*)p,     lo, __ATOMIC_RELAXED, __HIP_MEMORY_SCOPE_AGENT);
  __hip_atomic_store(((u64*)p)+1, hi, __ATOMIC_RELAXED, __HIP_MEMORY_SCOPE_AGENT);
}

// ---------------- weight packing ---------------------------------------------
__global__ void pack_w_kernel(const float* __restrict__ U1, const float* __restrict__ W2,
                              const float* __restrict__ U2, u16* __restrict__ U1p,
                              u16* __restrict__ UW2p)
{
  int idx = blockIdx.x*256 + threadIdx.x;
  int ln = idx & 63;
  int q8 = ((ln >> 4) << 3);
  int cl = ln & 15;
  if (idx < 16*128*64) {
    int kc = idx >> 13, ng = (idx >> 6) & 127;
    int row0 = kc*32 + q8, col = ng*16 + cl;
    u16* d = U1p + (size_t)idx*8;
    #pragma unroll
    for (int j=0;j<8;j++) d[j] = f2bf(U1[(size_t)(row0+j)*2048 + col]);
  } else {
    int i2 = idx - 16*128*64;
    if (i2 >= 32*128*64) return;
    int kc = i2 >> 13, ng = (i2 >> 6) & 127;
    int row0 = kc*32 + q8, col = ng*16 + cl;
    u16* d = UW2p + (size_t)i2*8;
    #pragma unroll
    for (int j=0;j<8;j++){
      int r = row0 + j;
      float v = (r < 512) ? W2[(size_t)r*2048 + col] : U2[(size_t)(r-512)*2048 + col];
      d[j] = f2bf(v);
    }
  }
}

__global__ void init_kernel(float* __restrict__ out, const float* __restrict__ fcb,
                            int* __restrict__ flags)
{
  int i = blockIdx.x*256 + threadIdx.x;
  if (i < 1024*FS) flags[i] = 0;
  if (i < B_*T_) out[i] = fcb[0];
}

// ============================ layer 1 (v10 structure) ========================
__device__ void run_l1_fs(char* smem, int blk, const float* __restrict__ inp,
                          const float* __restrict__ W1, const float* __restrict__ V,
                          const float* __restrict__ bias, char* __restrict__ ws)
{
  u16*  Bl   = (u16*)smem;                        // [16kc][8ngl][512]
  u16*  hlds = (u16*)(smem + 131072);             // 64 x 40
  float* wlds = (float*)(smem + 131072 + 6144);   // 4*32*6
  constexpr int RS = 40;
  const int tid = threadIdx.x, w = tid>>6, ln = tid&63, col = ln&15, quad = ln>>4;
  const int bi = blk & 7, hj = blk >> 3, h0 = hj*32, bg = bi*4 + w;

  const u16* Upak = (const u16*)(ws + OFF_U1P);
  const u16* H1f  = (const u16*)(ws + OFF_H1F);
  u16* Hw = (u16*)(ws + OFF_H1F);
  int* flag1 = (int*)(ws + OFF_FLAGS);
  const int* f1p = flag1 + (size_t)((bi*16 + (ln&15))*4 + w)*FS;  // producers, wave w
  int* myf = flag1 + (size_t)((bi*16 + hj)*4 + w)*FS;
  const bool a16 = ln < 16;
  int vl1 = 0;

  #pragma unroll
  for (int p=0;p<32;p++){
    int pid = w*32 + p, kc = pid>>3, ngl = pid&7;
    int ng = (ngl>>1)*32 + hj*2 + (ngl&1);
    async_cp16(Upak + ((size_t)(kc*128+ng)*64 + ln)*8, Bl + (size_t)pid*512);
  }
  for (int idx=tid; idx<4*32*6; idx+=256){
    int gate = idx/192, rem = idx%192, hcol = rem/6, k = rem%6;
    int gcol = gate*512 + h0 + hcol;
    wlds[idx] = (k==0)? bias[gcol] : (k<=4 ? V[(size_t)(k-1)*2048 + gcol] : W1[gcol]);
  }
  if (tid == 0) *(int*)(smem + SMEM_BASE) = 0;    // done counter

  float c[8];
  #pragma unroll
  for (int i=0;i<8;i++) c[i] = 0.f;
  const f32x4 vzero = {0.f,0.f,0.f,0.f};

  __syncthreads();   // one-time (heater waves join this barrier)
  __builtin_amdgcn_s_setprio(1);                  // compute waves: high prio

  for (int t=0; t<T_; t++){
    f32x4 acc[8];
    #pragma unroll
    for (int i=0;i<8;i++) acc[i] = vzero;

    if (t > 0){
      wpoll(f1p, a16, t, vl1);                              // per-wave, no barrier
      __builtin_amdgcn_fence(__ATOMIC_ACQUIRE, "workgroup");
      const u16* ab = H1f + (size_t)(t-1)*H_SLOT + (size_t)bg*16*512 + (size_t)ln*8;
      bf16x8 aw[8];
      #pragma unroll
      for (int i=0;i<8;i++) aw[i] = ldh<true>(ab + (size_t)i*512);
      #pragma unroll
      for (int kc=0; kc<16; kc++){
        bf16x8 av = aw[kc&7];
        if (kc < 8) aw[kc&7] = ldh<true>(ab + (size_t)(kc+8)*512);
        const u16* bb = Bl + (size_t)kc*8*512 + (size_t)ln*8;
        #pragma unroll
        for (int ngl=0; ngl<8; ngl++)
          acc[ngl] = __builtin_amdgcn_mfma_f32_16x16x32_bf16(
              av, *(const bf16x8*)(bb + (size_t)ngl*512), acc[ngl], 0,0,0);
      }
    }

    float iv[4][5];
    #pragma unroll
    for (int r=0;r<4;r++){
      const float* ip = inp + ((size_t)(bi*64 + w*16 + quad*4 + r)*T_ + t)*5;
      #pragma unroll
      for (int k=0;k<5;k++) iv[r][k] = ip[k];
    }
    #pragma unroll
    for (int hg=0; hg<2; hg++){
      float wv[4][6];
      #pragma unroll
      for (int gate=0; gate<4; gate++){
        const float* wp = wlds + (size_t)(gate*32 + hg*16 + col)*6;
        #pragma unroll
        for (int k=0;k<6;k++) wv[gate][k] = wp[k];
      }
      #pragma unroll
      for (int r=0;r<4;r++){
        float gv[4];
        #pragma unroll
        for (int gate=0; gate<4; gate++){
          gv[gate] = acc[gate*2+hg][r] + wv[gate][0]
                   + iv[r][0]*wv[gate][1] + iv[r][1]*wv[gate][2]
                   + iv[r][2]*wv[gate][3] + iv[r][3]*wv[gate][4]
                   + iv[r][4]*wv[gate][5];
        }
        float ig=sigm_f(gv[0]), fg=sigm_f(gv[1]), gg=tanh_ff(gv[2]), og=sigm_f(gv[3]);
        float cn = fg*c[hg*4+r] + ig*gg;
        c[hg*4+r] = cn;
        hlds[(size_t)(w*16 + quad*4 + r)*RS + hg*16 + col] = f2bf(og*tanh_ff(cn));
      }
    }
    // pack: same-wave transpose (wave-local rows, no barrier)
    {
      uint4 v = *(const uint4*)&hlds[(size_t)(w*16 + (ln&15))*RS + (ln>>4)*8];
      ring_st16(Hw + (size_t)t*H_SLOT + ((size_t)(bg*16 + hj)*64 + ln)*8, v);
    }
    drain_vm();
    if (ln == 0)
      __hip_atomic_store(myf, t+1, __ATOMIC_RELAXED, __HIP_MEMORY_SCOPE_AGENT);
  }
  if (ln == 0) atomicAdd((int*)(smem + SMEM_BASE), 1);   // signal heaters
}

// ============================ layer 2 (v10 structure) ========================
template<bool PLAIN>
__device__ __forceinline__ void l2_half(f32x4* accA, f32x4* accB, const u16* Bh,
                                        const u16* A, int bgA, int bgB, int ln)
{
  const u16* pA = A + (size_t)bgA*16*512 + (size_t)ln*8;
  const u16* pB = A + (size_t)bgB*16*512 + (size_t)ln*8;
  bf16x8 awA[8], awB[8];
  #pragma unroll
  for (int i=0;i<8;i++){
    awA[i] = ldh<PLAIN>(pA + (size_t)i*512);
    awB[i] = ldh<PLAIN>(pB + (size_t)i*512);
  }
  #pragma unroll
  for (int kc=0; kc<16; kc++){
    bf16x8 avA = awA[kc&7], avB = awB[kc&7];
    if (kc < 8){
      awA[kc&7] = ldh<PLAIN>(pA + (size_t)(kc+8)*512);
      awB[kc&7] = ldh<PLAIN>(pB + (size_t)(kc+8)*512);
    }
    const u16* bb = Bh + (size_t)kc*4*512 + (size_t)ln*8;
    #pragma unroll
    for (int ngl=0; ngl<4; ngl++){
      bf16x8 bf = *(const bf16x8*)(bb + (size_t)ngl*512);
      accA[ngl] = __builtin_amdgcn_mfma_f32_16x16x32_bf16(avA, bf, accA[ngl], 0,0,0);
      accB[ngl] = __builtin_amdgcn_mfma_f32_16x16x32_bf16(avB, bf, accB[ngl], 0,0,0);
    }
  }
}

template<bool H2F>
__device__ void run_l2_fs(char* smem, int blk2, const float* __restrict__ inp,
                          const float* __restrict__ V, const float* __restrict__ bias,
                          const float* __restrict__ fcw, char* __restrict__ ws,
                          float* __restrict__ out)
{
  u16*  Bl   = (u16*)smem;                        // [32kc][4ngl][512]
  u16*  hlds = (u16*)(smem + 131072);             // 128 x 24
  float* wlds = (float*)(smem + 131072 + 6144);   // 4*16*6
  constexpr int RS = 24;
  const int tid = threadIdx.x, w = tid>>6, ln = tid&63, col = ln&15, quad = ln>>4;
  const int bi2 = blk2 & 3, hj = blk2 >> 2, h0 = hj*16;
  const int bgA = bi2*8 + w, bgB = bgA + 4;

  const u16* Upak = (const u16*)(ws + OFF_UW2P);
  const u16* H1f  = (const u16*)(ws + OFF_H1F);
  const u16* H2b  = (const u16*)(ws + (H2F ? OFF_H2F : OFF_H2R));
  u16* Hw = (u16*)(ws + (H2F ? OFF_H2F : OFF_H2R));
  int* flag1 = (int*)(ws + OFF_FLAGS);
  int* flag2 = flag1 + 512*FS;
  const int* h1f = flag1 + (size_t)((bi2*32 + (ln&31))*4 + w)*FS;
  const int* h2f = flag2 + (size_t)((bi2*32 + (ln&31))*4 + w)*FS;
  int* myf = flag2 + (size_t)((bi2*32 + hj)*4 + w)*FS;
  const bool a32 = ln < 32;
  int vlh1 = 0, vlh2 = 0;

  #pragma unroll
  for (int p=0;p<32;p++){
    int pid = w*32 + p, kc = pid>>2, ngl = pid&3;
    int ng = ngl*32 + hj;
    async_cp16(Upak + ((size_t)(kc*128+ng)*64 + ln)*8, Bl + (size_t)pid*512);
  }
  for (int idx=tid; idx<4*16*6; idx+=256){
    int gate = idx/96, rem = idx%96, hcol = rem/6, k = rem%6;
    int gcol = gate*512 + h0 + hcol;
    wlds[idx] = (k==0)? bias[gcol] : (k<=4 ? V[(size_t)(k-1)*2048 + gcol] : 0.f);
  }
  const float fcwr = fcw[h0 + col];
  if (tid == 0) *(int*)(smem + SMEM_BASE) = 0;

  float c[8];
  #pragma unroll
  for (int i=0;i<8;i++) c[i] = 0.f;
  const f32x4 vzero = {0.f,0.f,0.f,0.f};

  __syncthreads();   // heater waves join
  __builtin_amdgcn_s_setprio(1);

  for (int t=0; t<T_; t++){
    f32x4 accA[4], accB[4];
    #pragma unroll
    for (int i=0;i<4;i++){ accA[i] = vzero; accB[i] = vzero; }

    wpoll(h1f, a32, t+1, vlh1);
    __builtin_amdgcn_fence(__ATOMIC_ACQUIRE, "workgroup");
    const u16* A1 = H1f + (size_t)t*H_SLOT;
    l2_half<true>(accA, accB, Bl, A1, bgA, bgB, ln);

    if (t > 0){
      wpoll(h2f, a32, t, vlh2);
      __builtin_amdgcn_fence(__ATOMIC_ACQUIRE, "workgroup");
      const u16* A2 = H2b + (H2F ? (size_t)(t-1)*H_SLOT : (size_t)((t-1)&1)*H_SLOT);
      l2_half<H2F>(accA, accB, Bl + (size_t)16*4*512, A2, bgA, bgB, ln);
    }

    float wv[4][5];
    #pragma unroll
    for (int gate=0; gate<4; gate++){
      const float* wp = wlds + (size_t)(gate*16 + col)*6;
      #pragma unroll
      for (int k=0;k<5;k++) wv[gate][k] = wp[k];
    }
    float fcp[2][4];
    #pragma unroll
    for (int sel=0; sel<2; sel++){
      const f32x4* ac = sel ? accB : accA;
      #pragma unroll
      for (int r=0;r<4;r++){
        const float* ip = inp + ((size_t)(bi2*128 + sel*64 + w*16 + quad*4 + r)*T_ + t)*5;
        float i0=ip[0], i1=ip[1], i2=ip[2], i3=ip[3];
        float gv[4];
        #pragma unroll
        for (int gate=0; gate<4; gate++){
          gv[gate] = ac[gate][r] + wv[gate][0]
                   + i0*wv[gate][1] + i1*wv[gate][2] + i2*wv[gate][3] + i3*wv[gate][4];
        }
        float ig=sigm_f(gv[0]), fg=sigm_f(gv[1]), gg=tanh_ff(gv[2]), og=sigm_f(gv[3]);
        float cn = fg*c[sel*4+r] + ig*gg;
        c[sel*4+r] = cn;
        float h = og*tanh_ff(cn);
        fcp[sel][r] = h*fcwr;
        hlds[(size_t)(sel*64 + w*16 + quad*4 + r)*RS + col] = f2bf(h);
      }
    }
    // publish h2[t] (same-wave transpose)
    {
      int sel = ln>>5, ch = (ln>>4)&1, m = ln&15;
      uint4 v = *(const uint4*)&hlds[(size_t)(sel*64 + w*16 + m)*RS + ch*8];
      int lp = ((hj&1)*2 + ch)*16 + m;
      int bgx = bi2*8 + sel*4 + w;
      u16* dst = Hw + (H2F ? (size_t)t*H_SLOT : (size_t)(t&1)*H_SLOT)
               + ((size_t)(bgx*16 + (hj>>1))*64 + lp)*8;
      ring_st16(dst, v);
    }
    drain_vm();
    if (ln == 0)
      __hip_atomic_store(myf, t+1, __ATOMIC_RELAXED, __HIP_MEMORY_SCOPE_AGENT);

    #pragma unroll
    for (int sel=0; sel<2; sel++){
      #pragma unroll
      for (int r=0;r<4;r++){
        float v = fcp[sel][r];
        #pragma unroll
        for (int m=1;m<16;m<<=1) v += __shfl_xor(v, m, 16);
        if (col == 0)
          atomicAdd(&out[(size_t)(bi2*128 + sel*64 + w*16 + quad*4 + r)*T_ + t], v);
      }
    }
  }
  if (ln == 0) atomicAdd((int*)(smem + SMEM_BASE), 1);
}

// ============================ heater waves ===================================
__device__ void heater(char* smem)
{
  volatile int* done = (int*)(smem + SMEM_BASE);
  __syncthreads();                          // join the one-time barrier
  float a = 1.0001f, b = 0.9999f, c0 = 1.0002f, d = 1.0003f, e = 0.9997f;
  while (*done < 4){
    #pragma unroll
    for (int i=0;i<64;i++){
      a  = __fmaf_rn(a,  b, 1.0e-7f);
      c0 = __fmaf_rn(c0, d, 1.0e-7f);
      e  = __fmaf_rn(e,  b, 1.0e-7f);
    }
    asm volatile("" :: "v"(a), "v"(c0), "v"(e));
  }
}

template<bool H2F>
__global__ void __launch_bounds__(512, 1)
lstm_main_v16(const float* __restrict__ inp, const float* __restrict__ W1,
              const float* __restrict__ V1, const float* __restrict__ b1,
              const float* __restrict__ V2, const float* __restrict__ b2,
              const float* __restrict__ fcw, char* __restrict__ ws, float* __restrict__ out)
{
  extern __shared__ char smem[];
  int blk = blockIdx.x;
  if (threadIdx.x >= 256){ heater(smem); return; }
  if (blk < 128) run_l1_fs(smem, blk, inp, W1, V1, b1, ws);
  else           run_l2_fs<H2F>(smem, blk-128, inp, V2, b2, fcw, ws, out);
}

// =========================== v9 fallback (proven 2221us, 256 thr) ============
__device__ void run_l1_r9(char* smem, int blk, const float* __restrict__ inp,
                          const float* __restrict__ W1, const float* __restrict__ V,
                          const float* __restrict__ bias, char* __restrict__ ws)
{
  u16*  Bl   = (u16*)smem;
  u16*  hlds = (u16*)(smem + 131072);
  float* wlds = (float*)(smem + 131072 + 6144);
  constexpr int RS = 40;
  const int tid = threadIdx.x, w = tid>>6, ln = tid&63, col = ln&15, quad = ln>>4;
  const int bi = blk & 7, hj = blk >> 3, h0 = hj*32, bg = bi*4 + w;

  const u16* Upak = (const u16*)(ws + OFF_U1P);
  const u16* H1r  = (const u16*)(ws + OFF_H1_R9);
  u16* Hw = (u16*)(ws + OFF_H1_R9);
  int* flag1 = (int*)(ws + OFF_FLAGS);
  int* flag2 = flag1 + 128*FS;
  const int* f1p = flag1 + (size_t)(bi*16 + (ln&15))*FS;
  const int* f2p = flag2 + (size_t)((bi>>1)*32 + (ln&31))*FS;
  int* myf = flag1 + (size_t)(bi*16 + hj)*FS;
  const bool a16 = ln < 16, a32 = ln < 32;
  int vl1 = 0, vlbp = 0;

  #pragma unroll
  for (int p=0;p<32;p++){
    int pid = w*32 + p, kc = pid>>3, ngl = pid&7;
    int ng = (ngl>>1)*32 + hj*2 + (ngl&1);
    async_cp16(Upak + ((size_t)(kc*128+ng)*64 + ln)*8, Bl + (size_t)pid*512);
  }
  for (int idx=tid; idx<4*32*6; idx+=256){
    int gate = idx/192, rem = idx%192, hcol = rem/6, k = rem%6;
    int gcol = gate*512 + h0 + hcol;
    wlds[idx] = (k==0)? bias[gcol] : (k<=4 ? V[(size_t)(k-1)*2048 + gcol] : W1[gcol]);
  }

  float c[8];
  #pragma unroll
  for (int i=0;i<8;i++) c[i] = 0.f;
  const f32x4 vzero = {0.f,0.f,0.f,0.f};

  for (int t=0; t<T_; t++){
    if (w == 0){
      if (t > 0)      wpoll(f1p, a16, t, vl1);
      if (t >= NRING) wpoll(f2p, a32, t-NRING+1, vlbp);
      __builtin_amdgcn_fence(__ATOMIC_ACQUIRE, "agent");
    }
    __syncthreads();

    f32x4 acc[8];
    #pragma unroll
    for (int i=0;i<8;i++) acc[i] = vzero;

    if (t > 0){
      const u16* ab = H1r + (size_t)((t-1)&7)*H_SLOT + (size_t)bg*16*512 + (size_t)ln*8;
      bf16x8 aw[8];
      #pragma unroll
      for (int i=0;i<8;i++) aw[i] = ldh<true>(ab + (size_t)i*512);
      #pragma unroll
      for (int kc=0; kc<16; kc++){
        bf16x8 av = aw[kc&7];
        if (kc < 8) aw[kc&7] = ldh<true>(ab + (size_t)(kc+8)*512);
        const u16* bb = Bl + (size_t)kc*8*512 + (size_t)ln*8;
        #pragma unroll
        for (int ngl=0; ngl<8; ngl++)
          acc[ngl] = __builtin_amdgcn_mfma_f32_16x16x32_bf16(
              av, *(const bf16x8*)(bb + (size_t)ngl*512), acc[ngl], 0,0,0);
      }
    }

    float iv[4][5];
    #pragma unroll
    for (int r=0;r<4;r++){
      const float* ip = inp + ((size_t)(bi*64 + w*16 + quad*4 + r)*T_ + t)*5;
      #pragma unroll
      for (int k=0;k<5;k++) iv[r][k] = ip[k];
    }
    #pragma unroll
    for (int hg=0; hg<2; hg++){
      float wv[4][6];
      #pragma unroll
      for (int gate=0; gate<4; gate++){
        const float* wp = wlds + (size_t)(gate*32 + hg*16 + col)*6;
        #pragma unroll
        for (int k=0;k<6;k++) wv[gate][k] = wp[k];
      }
      #pragma unroll
      for (int r=0;r<4;r++){
        float gv[4];
        #pragma unroll
        for (int gate=0; gate<4; gate++){
          gv[gate] = acc[gate*2+hg][r] + wv[gate][0]
                   + iv[r][0]*wv[gate][1] + iv[r][1]*wv[gate][2]
                   + iv[r][2]*wv[gate][3] + iv[r][3]*wv[gate][4]
                   + iv[r][4]*wv[gate][5];
        }
        float ig=sigm_f(gv[0]), fg=sigm_f(gv[1]), gg=tanh_ff(gv[2]), og=sigm_f(gv[3]);
        float cn = fg*c[hg*4+r] + ig*gg;
        c[hg*4+r] = cn;
        hlds[(size_t)(w*16 + quad*4 + r)*RS + hg*16 + col] = f2bf(og*tanh_ff(cn));
      }
    }
    {
      uint4 v = *(const uint4*)&hlds[(size_t)(w*16 + (ln&15))*RS + (ln>>4)*8];
      ring_st16(Hw + (size_t)(t&7)*H_SLOT + ((size_t)(bg*16 + hj)*64 + ln)*8, v);
    }
    __syncthreads();
    if (tid==0){
      __builtin_amdgcn_fence(__ATOMIC_RELEASE, "workgroup");
      __hip_atomic_store(myf, t+1, __ATOMIC_RELAXED, __HIP_MEMORY_SCOPE_AGENT);
    }
  }
}

__device__ void run_l2_r9(char* smem, int blk2, const float* __restrict__ inp,
                          const float* __restrict__ V, const float* __restrict__ bias,
                          const float* __restrict__ fcw, char* __restrict__ ws,
                          float* __restrict__ out)
{
  u16*  Bl   = (u16*)smem;
  u16*  hlds = (u16*)(smem + 131072);
  float* wlds = (float*)(smem + 131072 + 6144);
  constexpr int RS = 24;
  const int tid = threadIdx.x, w = tid>>6, ln = tid&63, col = ln&15, quad = ln>>4;
  const int bi2 = blk2 & 3, hj = blk2 >> 2, h0 = hj*16;
  const int bgA = bi2*8 + w, bgB = bgA + 4;

  const u16* Upak = (const u16*)(ws + OFF_UW2P);
  const u16* H1r  = (const u16*)(ws + OFF_H1_R9);
  const u16* H2r  = (const u16*)(ws + OFF_H2_R9);
  u16* Hw = (u16*)(ws + OFF_H2_R9);
  int* flag1 = (int*)(ws + OFF_FLAGS);
  int* flag2 = flag1 + 128*FS;
  const int* h1f = flag1 + (size_t)(bi2*32 + (ln&31))*FS;
  const int* h2f = flag2 + (size_t)(bi2*32 + (ln&31))*FS;
  int* myf = flag2 + (size_t)(bi2*32 + hj)*FS;
  const bool a32 = ln < 32;
  int vlh1 = 0, vlh2 = 0;

  #pragma unroll
  for (int p=0;p<32;p++){
    int pid = w*32 + p, kc = pid>>2, ngl = pid&3;
    int ng = ngl*32 + hj;
    async_cp16(Upak + ((size_t)(kc*128+ng)*64 + ln)*8, Bl + (size_t)pid*512);
  }
  for (int idx=tid; idx<4*16*6; idx+=256){
    int gate = idx/96, rem = idx%96, hcol = rem/6, k = rem%6;
    int gcol = gate*512 + h0 + hcol;
    wlds[idx] = (k==0)? bias[gcol] : (k<=4 ? V[(size_t)(k-1)*2048 + gcol] : 0.f);
  }
  const float fcwr = fcw[h0 + col];

  float c[8];
  #pragma unroll
  for (int i=0;i<8;i++) c[i] = 0.f;
  const f32x4 vzero = {0.f,0.f,0.f,0.f};

  for (int t=0; t<T_; t++){
    if (w == 0){
      wpoll(h1f, a32, t+1, vlh1);
      __builtin_amdgcn_fence(__ATOMIC_ACQUIRE, "agent");
    }
    __syncthreads();

    f32x4 accA[4], accB[4];
    #pragma unroll
    for (int i=0;i<4;i++){ accA[i] = vzero; accB[i] = vzero; }

    const u16* A1 = H1r + (size_t)(t&7)*H_SLOT;
    l2_half<true>(accA, accB, Bl, A1, bgA, bgB, ln);

    if (t > 0){
      wpoll(h2f, a32, t, vlh2);
      __builtin_amdgcn_fence(__ATOMIC_ACQUIRE, "workgroup");
      const u16* A2 = H2r + (size_t)((t-1)&1)*H_SLOT;
      l2_half<false>(accA, accB, Bl + (size_t)16*4*512, A2, bgA, bgB, ln);
    }

    float wv[4][5];
    #pragma unroll
    for (int gate=0; gate<4; gate++){
      const float* wp = wlds + (size_t)(gate*16 + col)*6;
      #pragma unroll
      for (int k=0;k<5;k++) wv[gate][k] = wp[k];
    }
    float fcp[2][4];
    #pragma unroll
    for (int sel=0; sel<2; sel++){
      const f32x4* ac = sel ? accB : accA;
      #pragma unroll
      for (int r=0;r<4;r++){
        const float* ip = inp + ((size_t)(bi2*128 + sel*64 + w*16 + quad*4 + r)*T_ + t)*5;
        float i0=ip[0], i1=ip[1], i2=ip[2], i3=ip[3];
        float gv[4];
        #pragma unroll
        for (int gate=0; gate<4; gate++){
          gv[gate] = ac[gate][r] + wv[gate][0]
                   + i0*wv[gate][1] + i1*wv[gate][2] + i2*wv[gate][3] + i3*wv[gate][4];
        }
        float ig=sigm_f(gv[0]), fg=sigm_f(gv[1]), gg=tanh_ff(gv[2]), og=sigm_f(gv[3]);
        float cn = fg*c[sel*4+r] + ig*gg;
        c[sel*4+r] = cn;
        float h = og*tanh_ff(cn);
        fcp[sel][r] = h*fcwr;
        hlds[(size_t)(sel*64 + w*16 + quad*4 + r)*RS + col] = f2bf(h);
      }
    }
    {
      int sel = ln>>5, ch = (ln>>4)&1, m = ln&15;
      uint4 v = *(const uint4*)&hlds[(size_t)(sel*64 + w*16 + m)*RS + ch*8];
      int lp = ((hj&1)*2 + ch)*16 + m;
      int bgx = bi2*8 + sel*4 + w;
      ring_st16(Hw + (size_t)(t&1)*H_SLOT + ((size_t)(bgx*16 + (hj>>1))*64 + lp)*8, v);
    }
    __syncthreads();
    if (tid==0){
      __builtin_amdgcn_fence(__ATOMIC_RELEASE, "workgroup");
      __hip_atomic_store(myf, t+1, __ATOMIC_RELAXED, __HIP_MEMORY_SCOPE_AGENT);
    }

    #pragma unroll
    for (int sel=0; sel<2; sel++){
      #pragma unroll
      for (int r=0;r<4;r++){
        float v = fcp[sel][r];
        #pragma unroll
        for (int m=1;m<16;m<<=1) v += __shfl_xor(v, m, 16);
        if (col == 0)
          atomicAdd(&out[(size_t)(bi2*128 + sel*64 + w*16 + quad*4 + r)*T_ + t], v);
      }
    }
  }
}

__global__ void __launch_bounds__(256, 1)
lstm_main_v9fb(const float* __restrict__ inp, const float* __restrict__ W1,
               const float* __restrict__ V1, const float* __restrict__ b1,
               const float* __restrict__ V2, const float* __restrict__ b2,
               const float* __restrict__ fcw, char* __restrict__ ws, float* __restrict__ out)
{
  extern __shared__ char smem[];
  int blk = blockIdx.x;
  if (blk < 128) run_l1_r9(smem, blk, inp, W1, V1, b1, ws);
  else           run_l2_r9(smem, blk-128, inp, V2, b2, fcw, ws, out);
}

extern "C" void kernel_launch(void* const* d_in, const int* in_sizes, int n_in,
                              void* d_out, int out_size, void* d_ws, size_t ws_size,
                              hipStream_t stream) {
  (void)in_sizes; (void)n_in; (void)out_size;
  const float* inp = (const float*)d_in[0];
  const float* W1  = (const float*)d_in[1];
  const float* U1  = (const float*)d_in[2];
  const float* V1  = (const float*)d_in[3];
  const float* b1  = (const float*)d_in[4];
  const float* W2  = (const float*)d_in[5];
  const float* U2  = (const float*)d_in[6];
  const float* V2  = (const float*)d_in[7];
  const float* b2  = (const float*)d_in[8];
  const float* fcw = (const float*)d_in[9];
  const float* fcb = (const float*)d_in[10];
  char* ws = (char*)d_ws;
  float* out = (float*)d_out;

  pack_w_kernel<<<1536, 256, 0, stream>>>(U1, W2, U2,
      (u16*)(ws + OFF_U1P), (u16*)(ws + OFF_UW2P));
  init_kernel<<<(B_*T_ + 255)/256, 256, 0, stream>>>(out, fcb, (int*)(ws + OFF_FLAGS));

  const size_t need_h1f  = (size_t)OFF_H1F + (size_t)T_*SLOT_B;   // ~92 MB
  const size_t need_both = (size_t)OFF_H2F + (size_t)T_*SLOT_B;   // ~176 MB

  if (ws_size >= need_both) {
    (void)hipFuncSetAttribute((const void*)lstm_main_v16<true>,
                              hipFuncAttributeMaxDynamicSharedMemorySize, SMEM_V14);
    lstm_main_v16<true><<<256, 512, SMEM_V14, stream>>>(inp, W1, V1, b1, V2, b2, fcw, ws, out);
  } else if (ws_size >= need_h1f) {
    (void)hipFuncSetAttribute((const void*)lstm_main_v16<false>,
                              hipFuncAttributeMaxDynamicSharedMemorySize, SMEM_V14);
    lstm_main_v16<false><<<256, 512, SMEM_V14, stream>>>(inp, W1, V1, b1, V2, b2, fcw, ws, out);
  } else {
    (void)hipFuncSetAttribute((const void*)lstm_main_v9fb,
                              hipFuncAttributeMaxDynamicSharedMemorySize, SMEM_V9);
    lstm_main_v9fb<<<256, 256, SMEM_V9, stream>>>(inp, W1, V1, b1, V2, b2, fcw, ws, out);
  }
}